// Round 13
// baseline (289.359 us; speedup 1.0000x reference)
//
#include <hip/hip_runtime.h>
#include <hip/hip_bf16.h>
#include <stdint.h>

// EvolvedLoopLinear: out[b,j] = sum_i x[b,i]*W[j,i] + b[j]
// M=8192, N=4096, K=4096. fp32 in/out, bf16 MFMA compute.
// Round 13: "reads-at-top" schedule. Per K-tile: [24 ds_reads (all
// fragments) -> MFMA Q0 (latency filler, counted waits) -> lgkmcnt(0)
// publish -> barrier -> stage all 4 regions of T+2 (8 gld_lds) -> MFMA
// Q1,Q2,Q3 stall-free -> vmcnt(8) -> barrier]. Two barriers per K-tile;
// ONE read-latency exposure per tile (vs 4 in r5-r9). Tile T is fully
// resident at the prev end-of-tile vmcnt+barrier (proven r5/r6 ledger),
// so top-of-tile reads are RAW-safe; stages after the mid barrier are
// WAR-safe (all waves' reads published). Steady vmcnt queue at tile end
// = [T-1's 8 (->T+1), T's 8 (->T+2)] -> vmcnt(8) drains T+1's data.
// LDS layout, swizzle (0 conflicts), region mapping, XCD swizzle,
// setprio, fence discipline: identical to r6/r9.

typedef __bf16 bf16_t;
typedef __bf16 bf16x8 __attribute__((ext_vector_type(8)));
typedef float  f32x4  __attribute__((ext_vector_type(4)));

#define M_DIM 8192
#define N_DIM 4096
#define K_DIM 4096
#define NT    (K_DIM / 64)    // 64 K-tiles of BK=64

#define GLD16(gp, lp) __builtin_amdgcn_global_load_lds(                    \
    (const __attribute__((address_space(1))) void*)(gp),                   \
    (__attribute__((address_space(3))) void*)(lp), 16, 0, 0)

#define MFMA(a, b, c) __builtin_amdgcn_mfma_f32_16x16x32_bf16((a), (b), (c), 0, 0, 0)

#define FENCE() asm volatile("" ::: "memory")

// ---------------- fp32 -> bf16 convert (vectorized, grid-stride) -----------
__global__ void __launch_bounds__(256) cvt_f32_bf16(
    const float* __restrict__ in, bf16_t* __restrict__ out, long n8)
{
    long i0 = (long)blockIdx.x * blockDim.x + threadIdx.x;
    long stride = (long)gridDim.x * blockDim.x;
    for (long i = i0; i < n8; i += stride) {
        const float4* p = (const float4*)(in + i * 8);
        float4 a = p[0];
        float4 b = p[1];
        bf16x8 o;
        o[0] = (bf16_t)a.x; o[1] = (bf16_t)a.y; o[2] = (bf16_t)a.z; o[3] = (bf16_t)a.w;
        o[4] = (bf16_t)b.x; o[5] = (bf16_t)b.y; o[6] = (bf16_t)b.z; o[7] = (bf16_t)b.w;
        *(bf16x8*)(out + i * 8) = o;
    }
}

// ---------------- 256x256 bf16 GEMM, reads-at-top, 2 barriers/K-tile -------
// LDS per parity buffer q (32768 el): Am0 @0, Am1 @8192, Bn0 @16384,
// Bn1 @24576. Chunk swizzle within each region: slot = chunk ^ (rho&7).
__global__ void __launch_bounds__(512, 1) gemm_256_rt(
    const bf16_t* __restrict__ A, const bf16_t* __restrict__ B,
    const float* __restrict__ bias, float* __restrict__ C)
{
    __shared__ bf16_t sm[2 * 32768];   // 128 KiB

    // XCD-aware bijective swizzle (gridDim = 512, divisible by 8)
    const int nwg = gridDim.x;
    const int bid = blockIdx.x;
    const int cpx = nwg >> 3;
    const int swz = (bid & 7) * cpx + (bid >> 3);
    const int NBN = N_DIM / 256;                       // 16
    const long blockM = (long)(swz / NBN) * 256;
    const long blockN = (long)(swz % NBN) * 256;

    const int t    = threadIdx.x;
    const int lane = t & 63;
    const int wid  = t >> 6;        // 8 waves: 2 (M) x 4 (N)
    const int wr   = wid >> 2;      // 0..1 -> 128 rows each
    const int wc   = wid & 3;       // 0..3 -> 64 cols each
    const int l15  = lane & 15;
    const int lk   = lane >> 4;     // 0..3

    // staging: LDS dest linear (t*16B within region line); global src row
    // per region mapping, chunk carries inverse swizzle. (r6 verbatim)
    const int cg  = (t & 7) ^ ((t >> 3) & 7);
    const int rA0 = (t >> 3);                                  // A line-0 row
    const int rB0 = ((t >> 3) & 31) | (((t >> 3) & 32) << 1);  // B line-0 row
    const bf16_t* gA = A + (blockM + rA0) * (long)K_DIM + cg * 8;
    const bf16_t* gB = B + (blockN + rB0) * (long)K_DIM + cg * 8;
    const int dstT = t * 8;         // 16 B per thread, linear within line

    // read side (r6 verbatim): fragment rho&7 == l15&7 for all fragments
    const int swzr = l15 & 7;
    const int cOff0 = ((0 * 4 + lk) ^ swzr) << 3;
    const int cOff1 = ((1 * 4 + lk) ^ swzr) << 3;
    const int aBase = wr * 4096 + l15 * 64;            // within Am region
    const int bBase = 16384 + wc * 2048 + l15 * 64;    // within buffer (Bn0)

    f32x4 acc[8][4] = {};

#define STAGE_A(q, tk, h) do {                                             \
    const bf16_t* _g = gA + (long)(tk) * 64 + (long)(h) * 64 * K_DIM;      \
    bf16_t* _l = (bf16_t*)sm + (q) * 32768 + (h) * 8192 + dstT;            \
    GLD16(_g,                _l);                                          \
    GLD16(_g + 128L * K_DIM, _l + 4096); } while (0)

#define STAGE_B(q, tk, h) do {                                             \
    const bf16_t* _g = gB + (long)(tk) * 64 + (long)(h) * 32 * K_DIM;      \
    bf16_t* _l = (bf16_t*)sm + (q) * 32768 + 16384 + (h) * 8192 + dstT;    \
    GLD16(_g,                _l);                                          \
    GLD16(_g + 128L * K_DIM, _l + 4096); } while (0)

    bf16x8 a0[4][2], a1[4][2], b0[2][2], b1[2][2];

    // read order: Q0's operands (b0, a0) FIRST so its counted wait covers
    // only the oldest 12 reads; b1/a1 land during Q0's MFMA window.
#define READ_ALL(s) do {                                                   \
    _Pragma("unroll") for (int n = 0; n < 2; ++n) {                        \
        b0[n][0] = *(const bf16x8*)((s) + bBase + n * 1024 + cOff0);       \
        b0[n][1] = *(const bf16x8*)((s) + bBase + n * 1024 + cOff1);       \
    }                                                                      \
    _Pragma("unroll") for (int m = 0; m < 4; ++m) {                        \
        a0[m][0] = *(const bf16x8*)((s) + aBase + m * 1024 + cOff0);       \
        a0[m][1] = *(const bf16x8*)((s) + aBase + m * 1024 + cOff1);       \
    }                                                                      \
    _Pragma("unroll") for (int n = 0; n < 2; ++n) {                        \
        b1[n][0] = *(const bf16x8*)((s) + bBase + 8192 + n * 1024 + cOff0);\
        b1[n][1] = *(const bf16x8*)((s) + bBase + 8192 + n * 1024 + cOff1);\
    }                                                                      \
    _Pragma("unroll") for (int m = 0; m < 4; ++m) {                        \
        a1[m][0] = *(const bf16x8*)((s) + 8192 + aBase + m * 1024 + cOff0);\
        a1[m][1] = *(const bf16x8*)((s) + 8192 + aBase + m * 1024 + cOff1);\
    } } while (0)

#define MFMA_Q0() do { _Pragma("unroll") for (int m = 0; m < 4; ++m)       \
    _Pragma("unroll") for (int kk = 0; kk < 2; ++kk)                       \
    _Pragma("unroll") for (int n = 0; n < 2; ++n)                          \
        acc[m][n] = MFMA(a0[m][kk], b0[n][kk], acc[m][n]); } while (0)
#define MFMA_Q1() do { _Pragma("unroll") for (int m = 0; m < 4; ++m)       \
    _Pragma("unroll") for (int kk = 0; kk < 2; ++kk)                       \
    _Pragma("unroll") for (int n = 0; n < 2; ++n)                          \
        acc[m][2 + n] = MFMA(a0[m][kk], b1[n][kk], acc[m][2 + n]); } while (0)
#define MFMA_Q2() do { _Pragma("unroll") for (int m = 0; m < 4; ++m)       \
    _Pragma("unroll") for (int kk = 0; kk < 2; ++kk)                       \
    _Pragma("unroll") for (int n = 0; n < 2; ++n)                          \
        acc[4 + m][n] = MFMA(a1[m][kk], b0[n][kk], acc[4 + m][n]); } while (0)
#define MFMA_Q3() do { _Pragma("unroll") for (int m = 0; m < 4; ++m)       \
    _Pragma("unroll") for (int kk = 0; kk < 2; ++kk)                       \
    _Pragma("unroll") for (int n = 0; n < 2; ++n)                          \
        acc[4 + m][2 + n] = MFMA(a1[m][kk], b1[n][kk], acc[4 + m][2 + n]); } while (0)

    // prologue: tile0 (8 loads) | tile1 (8 loads); vmcnt(8) = tile0 landed.
    STAGE_A(0, 0, 0); STAGE_A(0, 0, 1); STAGE_B(0, 0, 0); STAGE_B(0, 0, 1);
    FENCE();
    STAGE_A(1, 1, 0); STAGE_A(1, 1, 1); STAGE_B(1, 1, 0); STAGE_B(1, 1, 1);
    FENCE();
    asm volatile("s_waitcnt vmcnt(8)" ::: "memory");
    __builtin_amdgcn_sched_barrier(0);
    __builtin_amdgcn_s_barrier();
    FENCE();

    for (int tk = 0; tk < NT; ++tk) {
        const int q = tk & 1;
        const bf16_t* s = (const bf16_t*)sm + q * 32768;

        // ---- top: all 24 fragment reads of tile tk (RAW-safe: resident
        //      since the previous end-of-tile vmcnt+barrier) ----
        READ_ALL(s);

        // ---- Q0 as latency filler: compiler counted-waits on the oldest
        //      12 reads; the other 12 land under Q0's MFMA window ----
        __builtin_amdgcn_s_setprio(1);
        MFMA_Q0();
        __builtin_amdgcn_s_setprio(0);

        // ---- publish: own reads retired, then block-wide barrier ----
        asm volatile("s_waitcnt lgkmcnt(0)" ::: "memory");
        __builtin_amdgcn_sched_barrier(0);
        __builtin_amdgcn_s_barrier();
        FENCE();

        // ---- stage all 4 regions of tile tk+2 (WAR-free now) ----
        if (tk + 2 < NT) {
            STAGE_A(q, tk + 2, 0); STAGE_A(q, tk + 2, 1);
            STAGE_B(q, tk + 2, 0); STAGE_B(q, tk + 2, 1);
        }
        FENCE();

        // ---- remaining 48 MFMA: stall-free (operands in regs) ----
        __builtin_amdgcn_s_setprio(1);
        MFMA_Q1();
        MFMA_Q2();
        MFMA_Q3();
        __builtin_amdgcn_s_setprio(0);

        // ---- end-of-tile drain: queue = [tk-1's 8 (->tk+1), tk's 8] ----
        if (tk < NT - 2) asm volatile("s_waitcnt vmcnt(8)" ::: "memory");
        else             asm volatile("s_waitcnt vmcnt(0)" ::: "memory");
        __builtin_amdgcn_sched_barrier(0);
        __builtin_amdgcn_s_barrier();
        FENCE();
    }

#undef STAGE_A
#undef STAGE_B

    // epilogue: C/D layout col = lane&15, row = (lane>>4)*4 + j
    const long cb = blockN + wc * 64;
    float bv[4];
    long  cn[4];
#pragma unroll
    for (int n = 0; n < 4; ++n) {
        cn[n] = cb + n * 16 + l15;
        bv[n] = bias[cn[n]];
    }
#pragma unroll
    for (int m = 0; m < 8; ++m) {
        const long r0 = blockM + wr * 128 + m * 16 + lk * 4;
#pragma unroll
        for (int n = 0; n < 4; ++n)
#pragma unroll
            for (int j = 0; j < 4; ++j)
                C[(r0 + j) * (long)N_DIM + cn[n]] = acc[m][n][j] + bv[n];
    }
}

// ---------------- fp32 fallback (only if ws too small) ---------------------
__global__ void __launch_bounds__(256) gemm_f32_fallback(
    const float* __restrict__ A, const float* __restrict__ W,
    const float* __restrict__ bias, float* __restrict__ C)
{
    __shared__ float sA[64][17];
    __shared__ float sB[64][17];
    const int bm = blockIdx.y, bn = blockIdx.x;
    const int t = threadIdx.x;
    const int tx = t & 15, ty = t >> 4;
    const long row0 = (long)bm * 64, col0 = (long)bn * 64;
    float acc[4][4] = {};
    for (int kt = 0; kt < K_DIM; kt += 16) {
        const int r = t >> 2, c = (t & 3) * 4;
        float4 a4 = *(const float4*)&A[(row0 + r) * K_DIM + kt + c];
        float4 b4 = *(const float4*)&W[(col0 + r) * K_DIM + kt + c];
        sA[r][c] = a4.x; sA[r][c + 1] = a4.y; sA[r][c + 2] = a4.z; sA[r][c + 3] = a4.w;
        sB[r][c] = b4.x; sB[r][c + 1] = b4.y; sB[r][c + 2] = b4.z; sB[r][c + 3] = b4.w;
        __syncthreads();
#pragma unroll
        for (int kk = 0; kk < 16; ++kk) {
            float av[4], bv[4];
#pragma unroll
            for (int i = 0; i < 4; ++i) av[i] = sA[ty * 4 + i][kk];
#pragma unroll
            for (int j = 0; j < 4; ++j) bv[j] = sB[tx * 4 + j][kk];
#pragma unroll
            for (int i = 0; i < 4; ++i)
#pragma unroll
                for (int j = 0; j < 4; ++j) acc[i][j] += av[i] * bv[j];
        }
        __syncthreads();
    }
#pragma unroll
    for (int i = 0; i < 4; ++i)
#pragma unroll
        for (int j = 0; j < 4; ++j)
            C[(row0 + ty * 4 + i) * N_DIM + col0 + tx * 4 + j] =
                acc[i][j] + bias[col0 + tx * 4 + j];
}

extern "C" void kernel_launch(void* const* d_in, const int* in_sizes, int n_in,
                              void* d_out, int out_size, void* d_ws, size_t ws_size,
                              hipStream_t stream)
{
    const float* x = (const float*)d_in[0];   // [8192, 4096]
    const float* W = (const float*)d_in[1];   // [4096, 4096]
    const float* b = (const float*)d_in[2];   // [4096]
    float* out = (float*)d_out;               // [8192, 4096] fp32

    const long xe = (long)M_DIM * K_DIM;
    const long we = (long)N_DIM * K_DIM;
    const size_t need = (size_t)(xe + we) * sizeof(bf16_t);  // ~96 MiB

    if (ws_size >= need) {
        bf16_t* xb = (bf16_t*)d_ws;
        bf16_t* wb = xb + xe;
        cvt_f32_bf16<<<2048, 256, 0, stream>>>(x, xb, xe / 8);
        cvt_f32_bf16<<<1024, 256, 0, stream>>>(W, wb, we / 8);
        gemm_256_rt<<<(M_DIM / 256) * (N_DIM / 256), 512, 0, stream>>>(xb, wb, b, out);
    } else {
        dim3 grid(N_DIM / 64, M_DIM / 64);
        gemm_f32_fallback<<<grid, 256, 0, stream>>>(x, W, b, out);
    }
}